// Round 8
// baseline (1222.486 us; speedup 1.0000x reference)
//
#include <hip/hip_runtime.h>
#include <hip/hip_fp16.h>
#include <cstdint>
#include <cstddef>

// ---------------------------------------------------------------------------
// GraphToGraph: edge-MLP scoring -> normalized spmm x5 -> directed min-label
// propagation -> group compaction -> group means.
// N=50000, E=400000, CON=128, STR=64, HID=128.
// fp16 payloads for gather-bound kernels; score sign stays f32-exact via a
// cooperative fallback. Multi-block scans. k_proj stages W1 slabs in LDS
// (global-latency stall removal); k_edge is 16-lanes-per-edge (2-deep load
// chain instead of 32 serial loads).
// ---------------------------------------------------------------------------

// init: assemble F0 = [con | struc] (N x 192, fp16), per-node scalars
__global__ void k_init(const float* __restrict__ con, const float* __restrict__ str,
                       __half* __restrict__ F, float* __restrict__ sums,
                       int* __restrict__ cnt, int* __restrict__ g, int N) {
  int i = blockIdx.x * blockDim.x + threadIdx.x;
  int total = N * 192;
  if (i < total) {
    int n = i / 192, f = i - n * 192;
    float v = (f < 128) ? con[n * 128 + f] : str[n * 64 + (f - 128)];
    F[i] = __float2half_rn(v);
  }
  if (i < N) { sums[i] = 1.0f; cnt[i] = 1; g[i] = i; }
}

// per-node projection: PQ[n][0:128] = con[n] @ W1[0:128,:] + b1
//                      PQ[n][128:256] = con[n] @ W1[128:256,:]
// 32 nodes per block; W1 staged in LDS by 32-k slabs (removes per-k-chunk
// L2 latency stalls). Writes f32 (exact fallback) AND fp16 copies.
__global__ __launch_bounds__(256) void k_proj(const float* __restrict__ con,
                                              const float* __restrict__ W1,
                                              const float* __restrict__ b1,
                                              float* __restrict__ PQf,
                                              __half* __restrict__ PQh, int N) {
  __shared__ float cs[32][128];     // 16 KB con tile
  __shared__ float ws[32 * 256];    // 32 KB W1 slab (rows k0..k0+32, both halves)
  int n0 = blockIdx.x * 32;
  for (int t = threadIdx.x; t < 32 * 128; t += 256) {
    int tn = t >> 7, k = t & 127;
    int node = n0 + tn;
    cs[tn][k] = (node < N) ? con[node * 128 + k] : 0.0f;
  }
  int j = threadIdx.x;
  float acc[32];
#pragma unroll
  for (int t = 0; t < 32; ++t) acc[t] = 0.0f;

  for (int k0 = 0; k0 < 128; k0 += 32) {
    __syncthreads();
    // cooperative W1 slab load: ws[kk*256 + c]; c<128 -> top half row k0+kk,
    // c>=128 -> bottom half. Coalesced float4 bursts (8 per thread).
    for (int t4 = threadIdx.x; t4 < 2048; t4 += 256) {
      int f = t4 * 4;
      int kk = f >> 8;
      int c = f & 255;
      const float* srcp = (c < 128) ? &W1[(k0 + kk) * 128 + c]
                                    : &W1[16384 + (k0 + kk) * 128 + (c - 128)];
      *(float4*)&ws[f] = *(const float4*)srcp;
    }
    __syncthreads();
#pragma unroll
    for (int kk = 0; kk < 32; kk += 4) {
      float w0 = ws[(kk + 0) * 256 + j];
      float w1v = ws[(kk + 1) * 256 + j];
      float w2v = ws[(kk + 2) * 256 + j];
      float w3v = ws[(kk + 3) * 256 + j];
#pragma unroll
      for (int t = 0; t < 32; ++t) {
        const float4 c4 = *reinterpret_cast<const float4*>(&cs[t][k0 + kk]);
        acc[t] += c4.x * w0 + c4.y * w1v + c4.z * w2v + c4.w * w3v;
      }
    }
  }
  float bj = (j < 128) ? b1[j] : 0.0f;
#pragma unroll
  for (int t = 0; t < 32; ++t) {
    int node = n0 + t;
    if (node < N) {
      float v = acc[t] + bj;
      PQf[(size_t)node * 256 + j] = v;
      PQh[(size_t)node * 256 + j] = __float2half_rn(v);
    }
  }
}

// edge scoring: 16 lanes per edge. Lane ll owns hidden elems [ll*8, ll*8+8):
// one uint4 of P, one of Q (2-deep load chain), 8 FMAs, 4-step shfl reduce.
// |raw| < 3e-3 -> cooperative exact f32 recompute (connectivity f32-exact).
__global__ __launch_bounds__(256) void k_edge(const int* __restrict__ src, const int* __restrict__ dst,
                                              const __half* __restrict__ PQ,
                                              const float* __restrict__ PQf,
                                              const float* __restrict__ W2,
                                              const float* __restrict__ b2,
                                              float* __restrict__ scores,
                                              float* __restrict__ sums, int* __restrict__ cnt,
                                              int* __restrict__ pos_s, int* __restrict__ pos_d,
                                              int* __restrict__ pos_cnt, int E) {
  int t = blockIdx.x * 256 + threadIdx.x;
  int e = t >> 4;
  int ll = t & 15;
  if (e >= E) return;
  int s = src[e], d = dst[e];
  if (d <= s) { if (ll == 0) scores[e] = 0.0f; return; }
  const uint4* P = (const uint4*)(PQ + (size_t)s * 256);
  const uint4* Q = (const uint4*)(PQ + (size_t)d * 256 + 128);
  const float4* W = (const float4*)W2;
  uint4 pu = P[ll];
  uint4 qu = Q[ll];
  float4 wa = W[2 * ll], wb = W[2 * ll + 1];
  float2 p0 = __half22float2(*(const __half2*)&pu.x);
  float2 p1 = __half22float2(*(const __half2*)&pu.y);
  float2 p2 = __half22float2(*(const __half2*)&pu.z);
  float2 p3 = __half22float2(*(const __half2*)&pu.w);
  float2 q0 = __half22float2(*(const __half2*)&qu.x);
  float2 q1 = __half22float2(*(const __half2*)&qu.y);
  float2 q2 = __half22float2(*(const __half2*)&qu.z);
  float2 q3 = __half22float2(*(const __half2*)&qu.w);
  float acc = fmaxf(p0.x + q0.x, 0.f) * wa.x + fmaxf(p0.y + q0.y, 0.f) * wa.y
            + fmaxf(p1.x + q1.x, 0.f) * wa.z + fmaxf(p1.y + q1.y, 0.f) * wa.w
            + fmaxf(p2.x + q2.x, 0.f) * wb.x + fmaxf(p2.y + q2.y, 0.f) * wb.y
            + fmaxf(p3.x + q3.x, 0.f) * wb.z + fmaxf(p3.y + q3.y, 0.f) * wb.w;
  acc += __shfl_xor(acc, 1, 64);
  acc += __shfl_xor(acc, 2, 64);
  acc += __shfl_xor(acc, 4, 64);
  acc += __shfl_xor(acc, 8, 64);
  float raw = acc + b2[0];
  if (fabsf(raw) < 3e-3f) {   // borderline: cooperative exact f32 recompute
    const float4* Pf = (const float4*)(PQf + (size_t)s * 256);
    const float4* Qf = (const float4*)(PQf + (size_t)d * 256 + 128);
    float4 a0 = Pf[2 * ll], a1 = Pf[2 * ll + 1];
    float4 c0 = Qf[2 * ll], c1 = Qf[2 * ll + 1];
    float a2 = fmaxf(a0.x + c0.x, 0.f) * wa.x + fmaxf(a0.y + c0.y, 0.f) * wa.y
             + fmaxf(a0.z + c0.z, 0.f) * wa.z + fmaxf(a0.w + c0.w, 0.f) * wa.w
             + fmaxf(a1.x + c1.x, 0.f) * wb.x + fmaxf(a1.y + c1.y, 0.f) * wb.y
             + fmaxf(a1.z + c1.z, 0.f) * wb.z + fmaxf(a1.w + c1.w, 0.f) * wb.w;
    a2 += __shfl_xor(a2, 1, 64);
    a2 += __shfl_xor(a2, 2, 64);
    a2 += __shfl_xor(a2, 4, 64);
    a2 += __shfl_xor(a2, 8, 64);
    raw = a2 + b2[0];
  }
  if (ll == 0) {
    float sc = fmaxf(raw, 0.0f);
    scores[e] = sc;
    if (sc > 0.0f) {
      atomicAdd(&sums[s], sc);
      atomicAdd(&sums[d], sc);
      atomicAdd(&cnt[s], 1);
      atomicAdd(&cnt[d], 1);
      int p = atomicAdd(pos_cnt, 1);
      pos_s[p] = s; pos_d[p] = d;
    }
  }
}

__device__ __forceinline__ int wave_iscan(int v) {
  int l = threadIdx.x & 63;
#pragma unroll
  for (int o = 1; o < 64; o <<= 1) {
    int t = __shfl_up(v, o, 64);
    if (l >= o) v += t;
  }
  return v;
}

// ---- 3-phase multi-block exclusive scan over N elements ----
__global__ __launch_bounds__(1024) void k_scan_red(int mode, const int* __restrict__ cnt,
                                                   const int* __restrict__ g,
                                                   int* __restrict__ bsum, int N) {
  __shared__ int wsum[16];
  int i = blockIdx.x * 1024 + threadIdx.x;
  int v = 0;
  if (i < N) v = (mode == 0) ? cnt[i] : ((g[i] == i) ? 1 : 0);
  int incl = wave_iscan(v);
  int wid = threadIdx.x >> 6;
  if ((threadIdx.x & 63) == 63) wsum[wid] = incl;
  __syncthreads();
  if (threadIdx.x == 0) {
    int t = 0;
#pragma unroll
    for (int k = 0; k < 16; ++k) t += wsum[k];
    bsum[blockIdx.x] = t;
  }
}

__global__ __launch_bounds__(64) void k_scan_mid(int mode, const int* __restrict__ bsum,
                                                 int* __restrict__ bexcl, int NB,
                                                 int* __restrict__ rowp, int N) {
  int l = threadIdx.x;
  int v = (l < NB) ? bsum[l] : 0;
  int incl = wave_iscan(v);
  if (l < NB) bexcl[l] = incl - v;
  if (l == 63 && mode == 0) rowp[N] = incl;   // grand total
}

__global__ __launch_bounds__(1024) void k_scan_out(int mode, const int* __restrict__ cnt,
                                                   const int* __restrict__ g,
                                                   const float* __restrict__ sums,
                                                   const int* __restrict__ bexcl,
                                                   int* __restrict__ rowp, int* __restrict__ fillp,
                                                   int* __restrict__ col, float* __restrict__ wt,
                                                   int* __restrict__ rank, int N) {
  __shared__ int wsum[16];
  int i = blockIdx.x * 1024 + threadIdx.x;
  int v = 0;
  if (i < N) v = (mode == 0) ? cnt[i] : ((g[i] == i) ? 1 : 0);
  int incl = wave_iscan(v);
  int wid = threadIdx.x >> 6;
  if ((threadIdx.x & 63) == 63) wsum[wid] = incl;
  __syncthreads();
  if (threadIdx.x < 64) {
    int l = threadIdx.x;
    int sv = (l < 16) ? wsum[l] : 0;
#pragma unroll
    for (int o = 1; o < 16; o <<= 1) {
      int t = __shfl_up(sv, o, 64);
      if (l >= o) sv += t;
    }
    if (l < 16) wsum[l] = sv;
  }
  __syncthreads();
  int wexcl = (wid == 0) ? 0 : wsum[wid - 1];
  int excl = bexcl[blockIdx.x] + wexcl + incl - v;
  if (i < N) {
    if (mode == 0) {
      rowp[i] = excl;
      fillp[i] = excl + 1;       // slot 0 of each row = self loop
      col[excl] = i;
      wt[excl] = 1.0f / sums[i];
    } else {
      rank[i] = excl;
    }
  }
}

// scatter positive edges (both directions) into CSR with normalized weights
__global__ void k_fill(const int* __restrict__ src, const int* __restrict__ dst,
                       const float* __restrict__ scores, const float* __restrict__ sums,
                       int* __restrict__ fillp, int* __restrict__ col, float* __restrict__ wt,
                       int E) {
  int e = blockIdx.x * blockDim.x + threadIdx.x;
  if (e >= E) return;
  float sc = scores[e];
  if (sc <= 0.0f) return;
  int s = src[e], d = dst[e];
  int p = atomicAdd(&fillp[s], 1);
  col[p] = d; wt[p] = sc / sums[s];
  int p2 = atomicAdd(&fillp[d], 1);
  col[p2] = s; wt[p2] = sc / sums[d];
}

// spmm over fp16 features: thread-per-(row, 8 halves) -> 24 threads/row.
__global__ __launch_bounds__(192) void k_spmm(const __half* __restrict__ Fin, __half* __restrict__ Fout,
                                              const int* __restrict__ rowp,
                                              const int* __restrict__ col,
                                              const float* __restrict__ wt, int N) {
  int tid = blockIdx.x * 192 + threadIdx.x;
  int row = tid / 24;
  int f8 = tid - row * 24;
  if (row >= N) return;
  const uint4* F8 = (const uint4*)Fin;
  int beg = rowp[row], end = rowp[row + 1];
  float a0 = 0.f, a1 = 0.f, a2 = 0.f, a3 = 0.f, a4 = 0.f, a5 = 0.f, a6 = 0.f, a7 = 0.f;
  int cnx = col[beg];
  float wnx = wt[beg];
  for (int idx = beg; idx < end; ++idx) {
    int c = cnx; float wv = wnx;
    if (idx + 1 < end) { cnx = col[idx + 1]; wnx = wt[idx + 1]; }
    uint4 v = F8[(size_t)c * 24 + f8];
    float2 v0 = __half22float2(*(const __half2*)&v.x);
    float2 v1 = __half22float2(*(const __half2*)&v.y);
    float2 v2 = __half22float2(*(const __half2*)&v.z);
    float2 v3 = __half22float2(*(const __half2*)&v.w);
    a0 += wv * v0.x; a1 += wv * v0.y; a2 += wv * v1.x; a3 += wv * v1.y;
    a4 += wv * v2.x; a5 += wv * v2.y; a6 += wv * v3.x; a7 += wv * v3.y;
  }
  uint4 o;
  *(__half2*)&o.x = __floats2half2_rn(a0, a1);
  *(__half2*)&o.y = __floats2half2_rn(a2, a3);
  *(__half2*)&o.z = __floats2half2_rn(a4, a5);
  *(__half2*)&o.w = __floats2half2_rn(a6, a7);
  ((uint4*)Fout)[(size_t)row * 24 + f8] = o;
}

// directed min-label propagation: edge sweeps + sound label-jumping.
__global__ void k_prop(const int* __restrict__ pos_s, const int* __restrict__ pos_d,
                       const int* __restrict__ pos_cnt, int* g, int N) {
  int i = blockIdx.x * blockDim.x + threadIdx.x;
  volatile int* gv = g;
  int P = *pos_cnt;
#pragma unroll
  for (int r = 0; r < 2; ++r) {
    if (i < P) {
      int s = pos_s[i], d = pos_d[i];
      int gs = gv[s];
      if (gs < gv[d]) atomicMin(&g[d], gs);
    }
    if (i < N) {
      int gi = gv[i];
      int gg = gv[gi];
      if (gg < gi) atomicMin(&g[i], gg);
      gi = gv[i];
      gg = gv[gi];
      if (gg < gi) atomicMin(&g[i], gg);
    }
  }
}

// per-group member counts (gcnt zeroed beforehand)
__global__ void k_gcnt(const int* __restrict__ g, const int* __restrict__ rank,
                       int* __restrict__ gcnt, int N) {
  int i = blockIdx.x * blockDim.x + threadIdx.x;
  if (i < N) atomicAdd(&gcnt[rank[g[i]]], 1);
}

// per-group inverse count
__global__ void k_inv(const int* __restrict__ gcnt, float* __restrict__ invc, int N) {
  int i = blockIdx.x * blockDim.x + threadIdx.x;
  if (i < N) invc[i] = 1.0f / (float)max(gcnt[i], 1);
}

// group mean accumulation: 64-node chunk per block, run-length coalesced
// atomics, mean fused via invc scale at run flush. F is fp16, out f32.
__global__ __launch_bounds__(192) void k_accum(const __half* __restrict__ F, const int* __restrict__ g,
                                               const int* __restrict__ rank,
                                               const float* __restrict__ invc,
                                               float* __restrict__ out, int N) {
  __shared__ int jbuf[64];
  int n0 = blockIdx.x * 64;
  if (threadIdx.x < 64) {
    int n = n0 + threadIdx.x;
    jbuf[threadIdx.x] = (n < N) ? rank[g[n]] : -1;
  }
  __syncthreads();
  int f = threadIdx.x;
  int lim = min(64, N - n0);
  float acc = 0.0f; int cur = -1;
  for (int k = 0; k < lim; ++k) {
    int j = jbuf[k];
    float v = __half2float(F[(size_t)(n0 + k) * 192 + f]);
    if (j != cur) {
      if (cur >= 0) atomicAdd(&out[(size_t)cur * 192 + f], acc * invc[cur]);
      cur = j; acc = v;
    } else {
      acc += v;
    }
  }
  if (cur >= 0) atomicAdd(&out[(size_t)cur * 192 + f], acc * invc[cur]);
}

extern "C" void kernel_launch(void* const* d_in, const int* in_sizes, int n_in,
                              void* d_out, int out_size, void* d_ws, size_t ws_size,
                              hipStream_t stream) {
  const float* con = (const float*)d_in[0];
  const float* str = (const float*)d_in[1];
  const float* W1  = (const float*)d_in[2];
  const float* b1  = (const float*)d_in[3];
  const float* W2  = (const float*)d_in[4];
  const float* b2  = (const float*)d_in[5];
  const int* edges = (const int*)d_in[6];
  int N = in_sizes[0] / 128;
  int E = in_sizes[6] / 2;
  const int* src = edges;
  const int* dst = edges + E;
  int NB = (N + 1023) / 1024;   // scan blocks (<=64)

  uint8_t* w = (uint8_t*)d_ws;
  size_t off = 0;
  auto alloc = [&](size_t bytes) -> void* {
    void* p = w + off;
    off += (bytes + 255) & ~(size_t)255;
    return p;
  };
  // Live-range aliasing:
  //  - Fb (fp16 feature ping buffer) aliases PQf (dead after k_edge).
  //  - PQh (fp16 PQ, dead after k_edge) overlaps the CSR/compaction arrays.
  __half* Fa    = (__half*)alloc((size_t)N * 192 * 2);
  float*  PQf   = (float*)alloc((size_t)N * 256 * 4);
  __half* Fb    = (__half*)PQf;
  float* scores = (float*)alloc((size_t)E * 4);
  float* sums   = (float*)alloc((size_t)N * 4);
  int*   cnt    = (int*)alloc((size_t)N * 4);
  int*   g      = (int*)alloc((size_t)N * 4);
  int*   pos_s  = (int*)alloc((size_t)E * 4);
  int*   pos_d  = (int*)alloc((size_t)E * 4);
  int*   pos_c  = (int*)alloc(256);
  int*   bsum   = (int*)alloc(64 * 4);
  int*   bexcl  = (int*)alloc(64 * 4);
  size_t mark = off;                       // overlap region start
  int*   colA   = (int*)alloc((2 * (size_t)E + N) * 4);
  float* wtA    = (float*)alloc((2 * (size_t)E + N) * 4);
  int*   rowp   = (int*)alloc((size_t)(N + 1) * 4);
  int*   fillp  = (int*)alloc((size_t)N * 4);
  int*   rank   = (int*)alloc((size_t)N * 4);
  int*   gcnt   = (int*)alloc((size_t)N * 4);
  float* invc   = (float*)alloc((size_t)N * 4);
  size_t pqh_bytes = (size_t)N * 256 * 2;
  if (off < mark + pqh_bytes) off = mark + ((pqh_bytes + 255) & ~(size_t)255);
  __half* PQh = (__half*)(w + mark);

  hipMemsetAsync(d_out, 0, (size_t)out_size * 4, stream);
  hipMemsetAsync(pos_c, 0, 4, stream);

  k_init<<<(N * 192 + 255) / 256, 256, 0, stream>>>(con, str, Fa, sums, cnt, g, N);
  k_proj<<<(N + 31) / 32, 256, 0, stream>>>(con, W1, b1, PQf, PQh, N);
  k_edge<<<((size_t)E * 16 + 255) / 256, 256, 0, stream>>>(src, dst, PQh, PQf, W2, b2,
                                                           scores, sums, cnt,
                                                           pos_s, pos_d, pos_c, E);
  // PQh dead from here; overlap region becomes CSR/compaction storage.
  k_scan_red<<<NB, 1024, 0, stream>>>(0, cnt, g, bsum, N);
  k_scan_mid<<<1, 64, 0, stream>>>(0, bsum, bexcl, NB, rowp, N);
  k_scan_out<<<NB, 1024, 0, stream>>>(0, cnt, g, sums, bexcl, rowp, fillp, colA, wtA, rank, N);
  k_fill<<<(E + 255) / 256, 256, 0, stream>>>(src, dst, scores, sums, fillp, colA, wtA, E);

  __half* fin = Fa; __half* fout = Fb;
  for (int it = 0; it < 5; ++it) {
    k_spmm<<<((size_t)N * 24 + 191) / 192, 192, 0, stream>>>(fin, fout, rowp, colA, wtA, N);
    __half* tmp = fin; fin = fout; fout = tmp;
  }

  for (int r = 0; r < 9; ++r)
    k_prop<<<(E + 255) / 256, 256, 0, stream>>>(pos_s, pos_d, pos_c, g, N);

  k_scan_red<<<NB, 1024, 0, stream>>>(1, cnt, g, bsum, N);
  k_scan_mid<<<1, 64, 0, stream>>>(1, bsum, bexcl, NB, rowp, N);
  k_scan_out<<<NB, 1024, 0, stream>>>(1, cnt, g, sums, bexcl, rowp, fillp, colA, wtA, rank, N);
  hipMemsetAsync(gcnt, 0, (size_t)N * 4, stream);
  k_gcnt<<<(N + 255) / 256, 256, 0, stream>>>(g, rank, gcnt, N);
  k_inv<<<(N + 255) / 256, 256, 0, stream>>>(gcnt, invc, N);
  k_accum<<<(N + 63) / 64, 192, 0, stream>>>(fin, g, rank, invc, (float*)d_out, N);
}

// Round 9
// 538.924 us; speedup vs baseline: 2.2684x; 2.2684x over previous
//
#include <hip/hip_runtime.h>
#include <hip/hip_fp16.h>
#include <cstdint>
#include <cstddef>

// ---------------------------------------------------------------------------
// GraphToGraph: edge-MLP scoring -> normalized spmm x5 -> directed min-label
// propagation -> group compaction -> group means.
// N=50000, E=400000, CON=128, STR=64, HID=128.
// Lessons applied: thread-per-edge with deep unrolled gathers (round 7 form;
// the 16-lane variant collapsed per-wave MLP and regressed 8x). pos-edge
// compaction via wave ballot (1 atomic/wave). k_proj uses 1-deep W1 register
// prefetch to cover the per-k-chunk global-load latency.
// ---------------------------------------------------------------------------

// init: assemble F0 = [con | struc] (N x 192, fp16), per-node scalars
__global__ void k_init(const float* __restrict__ con, const float* __restrict__ str,
                       __half* __restrict__ F, float* __restrict__ sums,
                       int* __restrict__ cnt, int* __restrict__ g, int N) {
  int i = blockIdx.x * blockDim.x + threadIdx.x;
  int total = N * 192;
  if (i < total) {
    int n = i / 192, f = i - n * 192;
    float v = (f < 128) ? con[n * 128 + f] : str[n * 64 + (f - 128)];
    F[i] = __float2half_rn(v);
  }
  if (i < N) { sums[i] = 1.0f; cnt[i] = 1; g[i] = i; }
}

// per-node projection (round-7 structure + 1-deep W1 register prefetch):
// PQ[n][0:128] = con[n] @ W1[0:128,:] + b1 ; PQ[n][128:256] = con[n] @ W1[128:256,:]
__global__ __launch_bounds__(256) void k_proj(const float* __restrict__ con,
                                              const float* __restrict__ W1,
                                              const float* __restrict__ b1,
                                              float* __restrict__ PQf,
                                              __half* __restrict__ PQh, int N) {
  __shared__ float cs[16][128];
  int n0 = blockIdx.x * 16;
  for (int t = threadIdx.x; t < 16 * 128; t += 256) {
    int tn = t >> 7, k = t & 127;
    int node = n0 + tn;
    cs[tn][k] = (node < N) ? con[node * 128 + k] : 0.0f;
  }
  __syncthreads();
  int j = threadIdx.x;
  int base = (j < 128) ? j : (128 * 128 + (j - 128));
  float acc[16];
#pragma unroll
  for (int t = 0; t < 16; ++t) acc[t] = 0.0f;
  // 1-deep prefetch: next chunk's W values load while current chunk's 64 FMAs run
  float w0 = W1[base + 0 * 128];
  float w1 = W1[base + 1 * 128];
  float w2 = W1[base + 2 * 128];
  float w3 = W1[base + 3 * 128];
  for (int k = 0; k < 128; k += 4) {
    float n0w = 0.f, n1w = 0.f, n2w = 0.f, n3w = 0.f;
    if (k < 124) {
      n0w = W1[base + (k + 4) * 128];
      n1w = W1[base + (k + 5) * 128];
      n2w = W1[base + (k + 6) * 128];
      n3w = W1[base + (k + 7) * 128];
    }
#pragma unroll
    for (int t = 0; t < 16; ++t) {
      const float4 c = *reinterpret_cast<const float4*>(&cs[t][k]);
      acc[t] += c.x * w0 + c.y * w1 + c.z * w2 + c.w * w3;
    }
    w0 = n0w; w1 = n1w; w2 = n2w; w3 = n3w;
  }
  float bj = (j < 128) ? b1[j] : 0.0f;
#pragma unroll
  for (int t = 0; t < 16; ++t) {
    int node = n0 + t;
    if (node < N) {
      float v = acc[t] + bj;
      PQf[(size_t)node * 256 + j] = v;
      PQh[(size_t)node * 256 + j] = __float2half_rn(v);
    }
  }
}

// edge scoring, thread-per-edge over fp16 PQ (round-7 form; deep unrolled
// gathers = high per-wave MLP). |raw| < 3e-3 -> exact f32 recompute.
// pos-edge compaction: wave-aggregated ballot, ONE pos_cnt atomic per wave.
__global__ __launch_bounds__(256) void k_edge(const int* __restrict__ src, const int* __restrict__ dst,
                                              const __half* __restrict__ PQ,
                                              const float* __restrict__ PQf,
                                              const float* __restrict__ W2,
                                              const float* __restrict__ b2,
                                              float* __restrict__ scores,
                                              float* __restrict__ sums, int* __restrict__ cnt,
                                              int* __restrict__ pos_s, int* __restrict__ pos_d,
                                              int* __restrict__ pos_cnt, int E) {
  int e = blockIdx.x * 256 + threadIdx.x;
  bool live = (e < E);
  int s = 0, d = 0;
  if (live) { s = src[e]; d = dst[e]; }
  bool scored = live && (d > s);
  float raw = -1.0f;
  if (scored) {
    const uint4* P = (const uint4*)(PQ + (size_t)s * 256);
    const uint4* Q = (const uint4*)(PQ + (size_t)d * 256 + 128);
    const float4* W = (const float4*)W2;
    float acc = 0.0f;
#pragma unroll 8
    for (int k = 0; k < 16; ++k) {
      uint4 pu = P[k];
      uint4 qu = Q[k];
      float4 wa = W[2 * k], wb = W[2 * k + 1];
      float2 p0 = __half22float2(*(const __half2*)&pu.x);
      float2 p1 = __half22float2(*(const __half2*)&pu.y);
      float2 p2 = __half22float2(*(const __half2*)&pu.z);
      float2 p3 = __half22float2(*(const __half2*)&pu.w);
      float2 q0 = __half22float2(*(const __half2*)&qu.x);
      float2 q1 = __half22float2(*(const __half2*)&qu.y);
      float2 q2 = __half22float2(*(const __half2*)&qu.z);
      float2 q3 = __half22float2(*(const __half2*)&qu.w);
      acc += fmaxf(p0.x + q0.x, 0.f) * wa.x + fmaxf(p0.y + q0.y, 0.f) * wa.y
           + fmaxf(p1.x + q1.x, 0.f) * wa.z + fmaxf(p1.y + q1.y, 0.f) * wa.w
           + fmaxf(p2.x + q2.x, 0.f) * wb.x + fmaxf(p2.y + q2.y, 0.f) * wb.y
           + fmaxf(p3.x + q3.x, 0.f) * wb.z + fmaxf(p3.y + q3.y, 0.f) * wb.w;
    }
    raw = acc + b2[0];
    if (fabsf(raw) < 3e-3f) {   // borderline: exact f32 recompute (rare)
      const float4* Pf = (const float4*)(PQf + (size_t)s * 256);
      const float4* Qf = (const float4*)(PQf + (size_t)d * 256 + 128);
      float acc2 = 0.0f;
      for (int k = 0; k < 32; ++k) {
        float4 p = Pf[k], q = Qf[k], w = W[k];
        acc2 += fmaxf(p.x + q.x, 0.f) * w.x + fmaxf(p.y + q.y, 0.f) * w.y
              + fmaxf(p.z + q.z, 0.f) * w.z + fmaxf(p.w + q.w, 0.f) * w.w;
      }
      raw = acc2 + b2[0];
    }
  }
  float sc = scored ? fmaxf(raw, 0.0f) : 0.0f;
  if (live) scores[e] = sc;
  bool pos = scored && (sc > 0.0f);
  if (pos) {
    atomicAdd(&sums[s], sc);
    atomicAdd(&sums[d], sc);
    atomicAdd(&cnt[s], 1);
    atomicAdd(&cnt[d], 1);
  }
  // wave-aggregated compaction: one pos_cnt atomic per wave
  unsigned long long m = __ballot(pos);
  if (pos) {
    int lane = threadIdx.x & 63;
    int rank = __popcll(m & ((1ULL << lane) - 1));
    int leader = __ffsll((long long)m) - 1;
    int bcast;
    if (lane == leader) bcast = atomicAdd(pos_cnt, __popcll(m));
    bcast = __shfl(bcast, leader, 64);
    pos_s[bcast + rank] = s;
    pos_d[bcast + rank] = d;
  }
}

__device__ __forceinline__ int wave_iscan(int v) {
  int l = threadIdx.x & 63;
#pragma unroll
  for (int o = 1; o < 64; o <<= 1) {
    int t = __shfl_up(v, o, 64);
    if (l >= o) v += t;
  }
  return v;
}

// ---- 3-phase multi-block exclusive scan over N elements ----
__global__ __launch_bounds__(1024) void k_scan_red(int mode, const int* __restrict__ cnt,
                                                   const int* __restrict__ g,
                                                   int* __restrict__ bsum, int N) {
  __shared__ int wsum[16];
  int i = blockIdx.x * 1024 + threadIdx.x;
  int v = 0;
  if (i < N) v = (mode == 0) ? cnt[i] : ((g[i] == i) ? 1 : 0);
  int incl = wave_iscan(v);
  int wid = threadIdx.x >> 6;
  if ((threadIdx.x & 63) == 63) wsum[wid] = incl;
  __syncthreads();
  if (threadIdx.x == 0) {
    int t = 0;
#pragma unroll
    for (int k = 0; k < 16; ++k) t += wsum[k];
    bsum[blockIdx.x] = t;
  }
}

__global__ __launch_bounds__(64) void k_scan_mid(int mode, const int* __restrict__ bsum,
                                                 int* __restrict__ bexcl, int NB,
                                                 int* __restrict__ rowp, int N) {
  int l = threadIdx.x;
  int v = (l < NB) ? bsum[l] : 0;
  int incl = wave_iscan(v);
  if (l < NB) bexcl[l] = incl - v;
  if (l == 63 && mode == 0) rowp[N] = incl;   // grand total
}

__global__ __launch_bounds__(1024) void k_scan_out(int mode, const int* __restrict__ cnt,
                                                   const int* __restrict__ g,
                                                   const float* __restrict__ sums,
                                                   const int* __restrict__ bexcl,
                                                   int* __restrict__ rowp, int* __restrict__ fillp,
                                                   int* __restrict__ col, float* __restrict__ wt,
                                                   int* __restrict__ rank, int N) {
  __shared__ int wsum[16];
  int i = blockIdx.x * 1024 + threadIdx.x;
  int v = 0;
  if (i < N) v = (mode == 0) ? cnt[i] : ((g[i] == i) ? 1 : 0);
  int incl = wave_iscan(v);
  int wid = threadIdx.x >> 6;
  if ((threadIdx.x & 63) == 63) wsum[wid] = incl;
  __syncthreads();
  if (threadIdx.x < 64) {
    int l = threadIdx.x;
    int sv = (l < 16) ? wsum[l] : 0;
#pragma unroll
    for (int o = 1; o < 16; o <<= 1) {
      int t = __shfl_up(sv, o, 64);
      if (l >= o) sv += t;
    }
    if (l < 16) wsum[l] = sv;
  }
  __syncthreads();
  int wexcl = (wid == 0) ? 0 : wsum[wid - 1];
  int excl = bexcl[blockIdx.x] + wexcl + incl - v;
  if (i < N) {
    if (mode == 0) {
      rowp[i] = excl;
      fillp[i] = excl + 1;       // slot 0 of each row = self loop
      col[excl] = i;
      wt[excl] = 1.0f / sums[i];
    } else {
      rank[i] = excl;
    }
  }
}

// scatter positive edges (both directions) into CSR with normalized weights
__global__ void k_fill(const int* __restrict__ src, const int* __restrict__ dst,
                       const float* __restrict__ scores, const float* __restrict__ sums,
                       int* __restrict__ fillp, int* __restrict__ col, float* __restrict__ wt,
                       int E) {
  int e = blockIdx.x * blockDim.x + threadIdx.x;
  if (e >= E) return;
  float sc = scores[e];
  if (sc <= 0.0f) return;
  int s = src[e], d = dst[e];
  int p = atomicAdd(&fillp[s], 1);
  col[p] = d; wt[p] = sc / sums[s];
  int p2 = atomicAdd(&fillp[d], 1);
  col[p2] = s; wt[p2] = sc / sums[d];
}

// spmm over fp16 features: thread-per-(row, 8 halves) -> 24 threads/row.
__global__ __launch_bounds__(192) void k_spmm(const __half* __restrict__ Fin, __half* __restrict__ Fout,
                                              const int* __restrict__ rowp,
                                              const int* __restrict__ col,
                                              const float* __restrict__ wt, int N) {
  int tid = blockIdx.x * 192 + threadIdx.x;
  int row = tid / 24;
  int f8 = tid - row * 24;
  if (row >= N) return;
  const uint4* F8 = (const uint4*)Fin;
  int beg = rowp[row], end = rowp[row + 1];
  float a0 = 0.f, a1 = 0.f, a2 = 0.f, a3 = 0.f, a4 = 0.f, a5 = 0.f, a6 = 0.f, a7 = 0.f;
  int cnx = col[beg];
  float wnx = wt[beg];
  for (int idx = beg; idx < end; ++idx) {
    int c = cnx; float wv = wnx;
    if (idx + 1 < end) { cnx = col[idx + 1]; wnx = wt[idx + 1]; }
    uint4 v = F8[(size_t)c * 24 + f8];
    float2 v0 = __half22float2(*(const __half2*)&v.x);
    float2 v1 = __half22float2(*(const __half2*)&v.y);
    float2 v2 = __half22float2(*(const __half2*)&v.z);
    float2 v3 = __half22float2(*(const __half2*)&v.w);
    a0 += wv * v0.x; a1 += wv * v0.y; a2 += wv * v1.x; a3 += wv * v1.y;
    a4 += wv * v2.x; a5 += wv * v2.y; a6 += wv * v3.x; a7 += wv * v3.y;
  }
  uint4 o;
  *(__half2*)&o.x = __floats2half2_rn(a0, a1);
  *(__half2*)&o.y = __floats2half2_rn(a2, a3);
  *(__half2*)&o.z = __floats2half2_rn(a4, a5);
  *(__half2*)&o.w = __floats2half2_rn(a6, a7);
  ((uint4*)Fout)[(size_t)row * 24 + f8] = o;
}

// directed min-label propagation: edge sweeps + sound label-jumping.
__global__ void k_prop(const int* __restrict__ pos_s, const int* __restrict__ pos_d,
                       const int* __restrict__ pos_cnt, int* g, int N) {
  int i = blockIdx.x * blockDim.x + threadIdx.x;
  volatile int* gv = g;
  int P = *pos_cnt;
#pragma unroll
  for (int r = 0; r < 2; ++r) {
    if (i < P) {
      int s = pos_s[i], d = pos_d[i];
      int gs = gv[s];
      if (gs < gv[d]) atomicMin(&g[d], gs);
    }
    if (i < N) {
      int gi = gv[i];
      int gg = gv[gi];
      if (gg < gi) atomicMin(&g[i], gg);
      gi = gv[i];
      gg = gv[gi];
      if (gg < gi) atomicMin(&g[i], gg);
    }
  }
}

// per-group member counts (gcnt zeroed beforehand)
__global__ void k_gcnt(const int* __restrict__ g, const int* __restrict__ rank,
                       int* __restrict__ gcnt, int N) {
  int i = blockIdx.x * blockDim.x + threadIdx.x;
  if (i < N) atomicAdd(&gcnt[rank[g[i]]], 1);
}

// per-group inverse count
__global__ void k_inv(const int* __restrict__ gcnt, float* __restrict__ invc, int N) {
  int i = blockIdx.x * blockDim.x + threadIdx.x;
  if (i < N) invc[i] = 1.0f / (float)max(gcnt[i], 1);
}

// group mean accumulation: 64-node chunk per block, run-length coalesced
// atomics, mean fused via invc scale at run flush. F is fp16, out f32.
__global__ __launch_bounds__(192) void k_accum(const __half* __restrict__ F, const int* __restrict__ g,
                                               const int* __restrict__ rank,
                                               const float* __restrict__ invc,
                                               float* __restrict__ out, int N) {
  __shared__ int jbuf[64];
  int n0 = blockIdx.x * 64;
  if (threadIdx.x < 64) {
    int n = n0 + threadIdx.x;
    jbuf[threadIdx.x] = (n < N) ? rank[g[n]] : -1;
  }
  __syncthreads();
  int f = threadIdx.x;
  int lim = min(64, N - n0);
  float acc = 0.0f; int cur = -1;
  for (int k = 0; k < lim; ++k) {
    int j = jbuf[k];
    float v = __half2float(F[(size_t)(n0 + k) * 192 + f]);
    if (j != cur) {
      if (cur >= 0) atomicAdd(&out[(size_t)cur * 192 + f], acc * invc[cur]);
      cur = j; acc = v;
    } else {
      acc += v;
    }
  }
  if (cur >= 0) atomicAdd(&out[(size_t)cur * 192 + f], acc * invc[cur]);
}

extern "C" void kernel_launch(void* const* d_in, const int* in_sizes, int n_in,
                              void* d_out, int out_size, void* d_ws, size_t ws_size,
                              hipStream_t stream) {
  const float* con = (const float*)d_in[0];
  const float* str = (const float*)d_in[1];
  const float* W1  = (const float*)d_in[2];
  const float* b1  = (const float*)d_in[3];
  const float* W2  = (const float*)d_in[4];
  const float* b2  = (const float*)d_in[5];
  const int* edges = (const int*)d_in[6];
  int N = in_sizes[0] / 128;
  int E = in_sizes[6] / 2;
  const int* src = edges;
  const int* dst = edges + E;
  int NB = (N + 1023) / 1024;   // scan blocks (<=64)

  uint8_t* w = (uint8_t*)d_ws;
  size_t off = 0;
  auto alloc = [&](size_t bytes) -> void* {
    void* p = w + off;
    off += (bytes + 255) & ~(size_t)255;
    return p;
  };
  // Live-range aliasing:
  //  - Fb (fp16 feature ping buffer) aliases PQf (dead after k_edge).
  //  - PQh (fp16 PQ, dead after k_edge) overlaps the CSR/compaction arrays.
  __half* Fa    = (__half*)alloc((size_t)N * 192 * 2);
  float*  PQf   = (float*)alloc((size_t)N * 256 * 4);
  __half* Fb    = (__half*)PQf;
  float* scores = (float*)alloc((size_t)E * 4);
  float* sums   = (float*)alloc((size_t)N * 4);
  int*   cnt    = (int*)alloc((size_t)N * 4);
  int*   g      = (int*)alloc((size_t)N * 4);
  int*   pos_s  = (int*)alloc((size_t)E * 4);
  int*   pos_d  = (int*)alloc((size_t)E * 4);
  int*   pos_c  = (int*)alloc(256);
  int*   bsum   = (int*)alloc(64 * 4);
  int*   bexcl  = (int*)alloc(64 * 4);
  size_t mark = off;                       // overlap region start
  int*   colA   = (int*)alloc((2 * (size_t)E + N) * 4);
  float* wtA    = (float*)alloc((2 * (size_t)E + N) * 4);
  int*   rowp   = (int*)alloc((size_t)(N + 1) * 4);
  int*   fillp  = (int*)alloc((size_t)N * 4);
  int*   rank   = (int*)alloc((size_t)N * 4);
  int*   gcnt   = (int*)alloc((size_t)N * 4);
  float* invc   = (float*)alloc((size_t)N * 4);
  size_t pqh_bytes = (size_t)N * 256 * 2;
  if (off < mark + pqh_bytes) off = mark + ((pqh_bytes + 255) & ~(size_t)255);
  __half* PQh = (__half*)(w + mark);

  hipMemsetAsync(d_out, 0, (size_t)out_size * 4, stream);
  hipMemsetAsync(pos_c, 0, 4, stream);

  k_init<<<(N * 192 + 255) / 256, 256, 0, stream>>>(con, str, Fa, sums, cnt, g, N);
  k_proj<<<(N + 15) / 16, 256, 0, stream>>>(con, W1, b1, PQf, PQh, N);
  k_edge<<<(E + 255) / 256, 256, 0, stream>>>(src, dst, PQh, PQf, W2, b2, scores, sums, cnt,
                                              pos_s, pos_d, pos_c, E);
  // PQh dead from here; overlap region becomes CSR/compaction storage.
  k_scan_red<<<NB, 1024, 0, stream>>>(0, cnt, g, bsum, N);
  k_scan_mid<<<1, 64, 0, stream>>>(0, bsum, bexcl, NB, rowp, N);
  k_scan_out<<<NB, 1024, 0, stream>>>(0, cnt, g, sums, bexcl, rowp, fillp, colA, wtA, rank, N);
  k_fill<<<(E + 255) / 256, 256, 0, stream>>>(src, dst, scores, sums, fillp, colA, wtA, E);

  __half* fin = Fa; __half* fout = Fb;
  for (int it = 0; it < 5; ++it) {
    k_spmm<<<((size_t)N * 24 + 191) / 192, 192, 0, stream>>>(fin, fout, rowp, colA, wtA, N);
    __half* tmp = fin; fin = fout; fout = tmp;
  }

  for (int r = 0; r < 9; ++r)
    k_prop<<<(E + 255) / 256, 256, 0, stream>>>(pos_s, pos_d, pos_c, g, N);

  k_scan_red<<<NB, 1024, 0, stream>>>(1, cnt, g, bsum, N);
  k_scan_mid<<<1, 64, 0, stream>>>(1, bsum, bexcl, NB, rowp, N);
  k_scan_out<<<NB, 1024, 0, stream>>>(1, cnt, g, sums, bexcl, rowp, fillp, colA, wtA, rank, N);
  hipMemsetAsync(gcnt, 0, (size_t)N * 4, stream);
  k_gcnt<<<(N + 255) / 256, 256, 0, stream>>>(g, rank, gcnt, N);
  k_inv<<<(N + 255) / 256, 256, 0, stream>>>(gcnt, invc, N);
  k_accum<<<(N + 63) / 64, 192, 0, stream>>>(fin, g, rank, invc, (float*)d_out, N);
}